// Round 6
// baseline (103.753 us; speedup 1.0000x reference)
//
#include <hip/hip_runtime.h>

// TanhAttention: B=4, L=512, D=256
//   scores[b,i,j] = sum_d tanh(H[b,i,d]+H[b,j,d]) * w[d] + bias
//   alpha = softmax_j(scores); r = alpha @ H
// Outputs concatenated: r (524288 floats) then alpha (1048576 floats).
//
// Math: sum_d w*tanh = (sum w) - 2*sum_d w*sigmoid, sigmoid = 1/(1+exp2(K*(hi+hj))),
//       K = 2*log2(e) folded into staged copies; softmax shift-invariance cancels
//       the constant (sum w + bias) -> bias unused. Scores symmetric -> upper tiles only.
//
// R5: occupancy attack on both kernels (R4 evidence: score 44us vs ~14us trans floor
// at 4.25 blocks/CU; softmax_r ~38us vs ~3us pipe work at 1 block/CU):
//  - score: 16x16 tiles, 128 thr, grid 2112 (8.25 blocks/CU, 16.5 waves/CU), DT=32.
//  - softmax_r: 512 blocks x 256 thr, 4 rows each (2 blocks/CU).

#define B_ 4
#define L_ 512
#define D_ 256
#define TS16 16
#define NT16 32         // L_/16
#define NTRI16 528      // 32*33/2 upper-triangular 16x16 tiles per batch
#define DT 32           // d-tile
#define NDT 8           // D_/DT
#define RSTR 18         // row stride in [dd][row] tiles (conflict-free)

typedef float v2f __attribute__((ext_vector_type(2)));
typedef float v4f __attribute__((ext_vector_type(4)));

__global__ __launch_bounds__(128) void score_kernel(
    const float* __restrict__ H, const float* __restrict__ w,
    float* __restrict__ sOut)
{
    __shared__ float his[2][DT][RSTR];   // K-scaled i-rows, [dd][row], 4.6 KB
    __shared__ float hjs[2][DT][RSTR];   // K-scaled j-rows, 4.6 KB
    __shared__ float ws[D_];             // 1 KB
    __shared__ float ts[TS16][TS16 + 2]; // transpose buffer for mirror

    const int tid = threadIdx.x;
    const int blk = blockIdx.x;          // 0 .. 4*528-1
    const int b   = blk / NTRI16;
    int t = blk - b * NTRI16;
    int ti = 0;
    while (t >= NT16 - ti) { t -= NT16 - ti; ++ti; }   // uniform, <=32 iters
    const int tj = ti + t;
    const int i0 = ti * TS16, j0 = tj * TS16;
    const float K = 2.8853900817779268f;  // 2*log2(e)
    const float* Hb = H + (size_t)b * L_ * D_;

    ws[tid] = w[tid];
    ws[tid + 128] = w[tid + 128];

    // staging: 32 rows (16 i + 16 j) x 32 d = 256 float4; each thread does 2
    // idx -> sr = idx>>3 (row 0..31), sq = idx&7 (quad)
    const int sr0 = tid >> 3,          sq0 = tid & 7;
    const int sr1 = (tid + 128) >> 3,  sq1 = tid & 7;   // sr1 = sr0+16 (j-set)
    const int row0 = (sr0 < TS16) ? (i0 + sr0) : (j0 + sr0 - TS16);
    const int row1 = j0 + sr1 - TS16;                   // always j-set
    const int rl0  = (sr0 < TS16) ? sr0 : (sr0 - TS16);
    const int rl1  = sr1 - TS16;
    float* const dst0 = (sr0 < TS16) ? &his[0][0][0] : &hjs[0][0][0];
    float* const dst1 = &hjs[0][0][0];
    const int bufStride = DT * RSTR;    // floats per buffer slot

    // prologue: stage tile 0
    {
        float4 a = *(const float4*)(Hb + row0 * D_ + 4 * sq0);
        float4 c = *(const float4*)(Hb + row1 * D_ + 4 * sq1);
        dst0[(4 * sq0 + 0) * RSTR + rl0] = a.x * K;
        dst0[(4 * sq0 + 1) * RSTR + rl0] = a.y * K;
        dst0[(4 * sq0 + 2) * RSTR + rl0] = a.z * K;
        dst0[(4 * sq0 + 3) * RSTR + rl0] = a.w * K;
        dst1[(4 * sq1 + 0) * RSTR + rl1] = c.x * K;
        dst1[(4 * sq1 + 1) * RSTR + rl1] = c.y * K;
        dst1[(4 * sq1 + 2) * RSTR + rl1] = c.z * K;
        dst1[(4 * sq1 + 3) * RSTR + rl1] = c.w * K;
    }
    __syncthreads();

    const int mi  = tid >> 3;   // 0..15 i within tile
    const int mj2 = tid & 7;    // j-pair; j = j0 + 2*mj2 + {0,1}

    v2f acc = (v2f){0.f, 0.f};

    for (int dt = 0; dt < NDT; ++dt) {
        const int cur   = dt & 1;
        const bool more = (dt + 1 < NDT);
        float4 n0, n1;
        if (more) {
            const int dn = (dt + 1) * DT;
            n0 = *(const float4*)(Hb + row0 * D_ + dn + 4 * sq0);
            n1 = *(const float4*)(Hb + row1 * D_ + dn + 4 * sq1);
        }

        #pragma unroll
        for (int dd = 0; dd < DT; ++dd) {
            const float hiv = his[cur][dd][mi];               // 16-distinct broadcast
            const float wv  = ws[dt * DT + dd];               // uniform broadcast
            v2f hj = *(const v2f*)&hjs[cur][dd][2 * mj2];     // b64, conflict-free
            v2f a = hj + hiv;                                 // K*(Hi+Hj)
            v2f e;
            e.x = __builtin_amdgcn_exp2f(a.x);
            e.y = __builtin_amdgcn_exp2f(a.y);
            v2f s = e + 1.0f;
            v2f r;
            r.x = __builtin_amdgcn_rcpf(s.x);
            r.y = __builtin_amdgcn_rcpf(s.y);
            acc += wv * r;
        }

        if (more) {
            const int nb = 1 - cur;
            float* d0 = dst0 + nb * bufStride;
            float* d1 = dst1 + nb * bufStride;
            d0[(4 * sq0 + 0) * RSTR + rl0] = n0.x * K;
            d0[(4 * sq0 + 1) * RSTR + rl0] = n0.y * K;
            d0[(4 * sq0 + 2) * RSTR + rl0] = n0.z * K;
            d0[(4 * sq0 + 3) * RSTR + rl0] = n0.w * K;
            d1[(4 * sq1 + 0) * RSTR + rl1] = n1.x * K;
            d1[(4 * sq1 + 1) * RSTR + rl1] = n1.y * K;
            d1[(4 * sq1 + 2) * RSTR + rl1] = n1.z * K;
            d1[(4 * sq1 + 3) * RSTR + rl1] = n1.w * K;
        }
        __syncthreads();
    }

    // shifted score pair (row constant cancels in softmax)
    v2f sv = -2.0f * acc;

    // upper write
    *(v2f*)&sOut[((size_t)b * L_ + i0 + mi) * L_ + j0 + 2 * mj2] = sv;

    // mirror write via LDS transpose (off-diagonal tiles; block-uniform branch)
    if (ti != tj) {
        *(v2f*)&ts[mi][2 * mj2] = sv;
        __syncthreads();
        const int jr = tid >> 3;      // 0..15 row of mirror tile
        const int c2 = tid & 7;       // i-pair
        v2f mv;
        mv.x = ts[2 * c2 + 0][jr];
        mv.y = ts[2 * c2 + 1][jr];
        *(v2f*)&sOut[((size_t)b * L_ + j0 + jr) * L_ + i0 + 2 * c2] = mv;
    }
}

// Phase 2: 512 blocks x 256 thr; 4 rows/block (2 blocks/CU). Softmax in place,
// then r-phase: wave w owns j in [128w,128w+128), partial r for all 4 rows
// (H[b] read once per block), LDS reduce across waves.
__global__ __launch_bounds__(256) void softmax_r_kernel(
    const float* __restrict__ H, float* __restrict__ rOut, float* __restrict__ aOut)
{
    __shared__ float sc[4][L_];      // alpha rows, 8 KB
    __shared__ float pr[4][4][D_];   // per-wave partial r, 16 KB

    const int tid  = threadIdx.x;
    const int blk  = blockIdx.x;     // 0..511
    const int b    = blk >> 7;
    const int i0   = (blk & 127) * 4;
    const int wv   = tid >> 6;       // wave 0..3
    const int lane = tid & 63;
    const float* Hb = H + (size_t)b * L_ * D_;
    const float L2E = 1.4426950408889634f;

    // ---- softmax: wave wv handles row wv ----
    {
        const int row = wv;
        float* aRow = aOut + ((size_t)b * L_ + i0 + row) * L_;
        float v[8];
        float m = -1e30f;
        #pragma unroll
        for (int k = 0; k < 8; ++k) {
            v[k] = aRow[lane + 64 * k];      // coalesced score reads (L2-hot)
            m = fmaxf(m, v[k]);
        }
        #pragma unroll
        for (int off = 1; off < 64; off <<= 1)
            m = fmaxf(m, __shfl_xor(m, off, 64));
        float s = 0.0f;
        #pragma unroll
        for (int k = 0; k < 8; ++k) {
            v[k] = __builtin_amdgcn_exp2f((v[k] - m) * L2E);
            s += v[k];
        }
        #pragma unroll
        for (int off = 1; off < 64; off <<= 1)
            s += __shfl_xor(s, off, 64);
        const float inv = __builtin_amdgcn_rcpf(s);
        #pragma unroll
        for (int k = 0; k < 8; ++k) {
            float a = v[k] * inv;
            sc[row][lane + 64 * k] = a;
            aRow[lane + 64 * k] = a;         // overwrite scores with alpha in place
        }
    }
    __syncthreads();

    // ---- r-phase: wave-cooperative over j ----
    const int jbase = 128 * wv;
    v4f racc[4];
    #pragma unroll
    for (int r = 0; r < 4; ++r) racc[r] = (v4f){0.f, 0.f, 0.f, 0.f};
    const v4f* Hb4 = (const v4f*)Hb;         // [512][64]

    for (int js = 0; js < 128; js += 4) {
        v4f av[4];
        #pragma unroll
        for (int r = 0; r < 4; ++r)
            av[r] = *(const v4f*)&sc[r][jbase + js];   // b128 uniform broadcast
        #pragma unroll
        for (int q = 0; q < 4; ++q) {
            v4f h = Hb4[(size_t)(jbase + js + q) * (D_ / 4) + lane];
            #pragma unroll
            for (int r = 0; r < 4; ++r)
                racc[r] += av[r][q] * h;
        }
    }
    #pragma unroll
    for (int r = 0; r < 4; ++r)
        *(v4f*)&pr[wv][r][4 * lane] = racc[r];
    __syncthreads();

    // ---- reduce 4 wave-partials, write r ----
    const int fq  = tid & 63;       // float4 index in D
    const int row = tid >> 6;       // 0..3
    v4f s = *(const v4f*)&pr[0][row][4 * fq];
    s += *(const v4f*)&pr[1][row][4 * fq];
    s += *(const v4f*)&pr[2][row][4 * fq];
    s += *(const v4f*)&pr[3][row][4 * fq];
    *(v4f*)&rOut[((size_t)b * L_ + i0 + row) * D_ + 4 * fq] = s;
}

extern "C" void kernel_launch(void* const* d_in, const int* in_sizes, int n_in,
                              void* d_out, int out_size, void* d_ws, size_t ws_size,
                              hipStream_t stream) {
    const float* H = (const float*)d_in[0];
    const float* w = (const float*)d_in[1];
    // d_in[2] (bias) unused: softmax shift-invariance cancels it.
    float* rOut = (float*)d_out;
    float* aOut = rOut + (size_t)B_ * L_ * D_;   // alpha region doubles as score scratch

    score_kernel<<<dim3(B_ * NTRI16), 128, 0, stream>>>(H, w, aOut);
    softmax_r_kernel<<<dim3(B_ * (L_ / 4)), 256, 0, stream>>>(H, rOut, aOut);
}

// Round 7
// 98.595 us; speedup vs baseline: 1.0523x; 1.0523x over previous
//
#include <hip/hip_runtime.h>

// TanhAttention: B=4, L=512, D=256
//   scores[b,i,j] = sum_d tanh(H[b,i,d]+H[b,j,d]) * w[d] + bias
//   alpha = softmax_j(scores); r = alpha @ H
// Outputs concatenated: r (524288 floats) then alpha (1048576 floats).
//
// Math: tanh(x) = 1 - 2/(1+e^{2x}); with E = exp2(K*h), K = 2*log2(e):
//   e^{2(hi+hj)} = Ei*Ej  ->  score_shifted = -2*sum_d w_d * rcp(fma(Ei,Ej,1))
// (softmax shift-invariance cancels sum(w)+bias -> bias unused; scores symmetric
//  -> only upper-triangular 32x32 tiles, mirrored).
//
// R6: R4/R5 were LDS-pipe bound (3 ds_reads/dd/wave ~18cyc -> 76K cyc/CU = 32us,
// matching measurement; occupancy changes were twice neutral). Fix:
//  - exp-factorization: 1 trans/elem (was 2): trans floor 14.5 -> 7.3 us
//  - d-blocked v4 micro-tile (4i x 2j x 4d): b128 LDS reads, ~2.25 cyc/elem
//  - interleaved row slots (stride 36) -> conflict-free, 16B-aligned b128
//  - w via wave-uniform global read -> s_load (0 LDS)
//  - 64-thread single-wave blocks, own LDS tile, double-buffered: ZERO barriers

#define B_ 4
#define L_ 512
#define D_ 256
#define TS 32
#define NTILE 16
#define NTRI 136
#define DT 32
#define NDT 8          // D_/DT
#define SSTR 36        // tile slot stride (floats): conflict-free + 16B-aligned
#define SCSTR 20       // score scratch stride

typedef float v4f __attribute__((ext_vector_type(4)));

__global__ __launch_bounds__(64) void score_kernel(
    const float* __restrict__ H, const float* __restrict__ w,
    float* __restrict__ sOut)
{
    __shared__ __align__(16) float tile[2][48 * SSTR];   // 13.8 KB (E values)

    const int lane = threadIdx.x;
    const int blk  = blockIdx.x;             // 0 .. B_*NTRI*2-1
    const int b    = blk / (NTRI * 2);
    int t2 = blk - b * (NTRI * 2);
    const int half = t2 & 1;
    int t = t2 >> 1;
    int ti = 0;
    while (t >= NTILE - ti) { t -= NTILE - ti; ++ti; }   // uniform, <=16 iters
    const int tj = ti + t;
    const int i0 = ti * TS;
    const int j0 = tj * TS + half * 16;      // 32i x 16j half-tile
    const float K = 2.8853900817779268f;     // 2*log2(e)
    const float* Hb = H + (size_t)b * L_ * D_;

    const int ig = lane >> 3, jg = lane & 7;

    // 48 staged rows (32 i-set + 16 j-set) x 32 d = 384 quads; this lane owns 6.
    // Interleaved LDS slots: i-row(ig,ii)->ii*8+ig ; j-row(jg,jj)->32+jj*8+jg
    int srow[6], scol[6], slot[6];
    #pragma unroll
    for (int s = 0; s < 6; ++s) {
        int idx = lane + 64 * s;
        int r = idx >> 3, c = idx & 7;
        srow[s] = (r < 32) ? (i0 + r) : (j0 + r - 32);
        scol[s] = 4 * c;
        slot[s] = (r < 32) ? ((r & 3) * 8 + (r >> 2))
                           : (32 + ((r - 32) & 1) * 8 + ((r - 32) >> 1));
    }

    // prologue: stage dt=0 (E = exp2(K*h))
    #pragma unroll
    for (int s = 0; s < 6; ++s) {
        float4 hv = *(const float4*)(Hb + srow[s] * D_ + scol[s]);
        v4f ev;
        ev.x = __builtin_amdgcn_exp2f(hv.x * K);
        ev.y = __builtin_amdgcn_exp2f(hv.y * K);
        ev.z = __builtin_amdgcn_exp2f(hv.z * K);
        ev.w = __builtin_amdgcn_exp2f(hv.w * K);
        *(v4f*)&tile[0][slot[s] * SSTR + scol[s]] = ev;
    }

    v4f acc[4][2];
    #pragma unroll
    for (int ii = 0; ii < 4; ++ii)
        #pragma unroll
        for (int jj = 0; jj < 2; ++jj) acc[ii][jj] = (v4f){0.f, 0.f, 0.f, 0.f};

    for (int dt = 0; dt < NDT; ++dt) {
        const int buf  = dt & 1;
        const bool more = (dt + 1 < NDT);
        float4 nx[6];
        if (more) {
            const int dn = (dt + 1) * DT;
            #pragma unroll
            for (int s = 0; s < 6; ++s)
                nx[s] = *(const float4*)(Hb + srow[s] * D_ + dn + scol[s]);
        }
        __builtin_amdgcn_wave_barrier();   // keep prior ds_writes before these reads

        #pragma unroll
        for (int q = 0; q < 8; ++q) {      // 4-d block per step
            const float4 wq = *(const float4*)(w + dt * DT + 4 * q);  // uniform -> s_load
            v4f wv; wv.x = wq.x; wv.y = wq.y; wv.z = wq.z; wv.w = wq.w;
            v4f Ei[4], Ej[2];
            #pragma unroll
            for (int ii = 0; ii < 4; ++ii)   // 8 distinct rows/instr, banks 4*ig+q -> free
                Ei[ii] = *(const v4f*)&tile[buf][(ii * 8 + ig) * SSTR + 4 * q];
            #pragma unroll
            for (int jj = 0; jj < 2; ++jj)
                Ej[jj] = *(const v4f*)&tile[buf][(32 + jj * 8 + jg) * SSTR + 4 * q];
            #pragma unroll
            for (int ii = 0; ii < 4; ++ii)
                #pragma unroll
                for (int jj = 0; jj < 2; ++jj) {
                    v4f den = Ei[ii] * Ej[jj] + 1.0f;   // fma(Ei,Ej,1)
                    v4f rr;
                    rr.x = __builtin_amdgcn_rcpf(den.x);
                    rr.y = __builtin_amdgcn_rcpf(den.y);
                    rr.z = __builtin_amdgcn_rcpf(den.z);
                    rr.w = __builtin_amdgcn_rcpf(den.w);
                    acc[ii][jj] += wv * rr;             // v4 over d, reduced at end
                }
        }

        if (more) {
            const int nb = 1 - buf;
            #pragma unroll
            for (int s = 0; s < 6; ++s) {
                v4f ev;
                ev.x = __builtin_amdgcn_exp2f(nx[s].x * K);
                ev.y = __builtin_amdgcn_exp2f(nx[s].y * K);
                ev.z = __builtin_amdgcn_exp2f(nx[s].z * K);
                ev.w = __builtin_amdgcn_exp2f(nx[s].w * K);
                *(v4f*)&tile[nb][slot[s] * SSTR + scol[s]] = ev;
            }
        }
    }

    // ---- epilogue: shifted scores -> LDS scratch (reuse tile[0]; last reads hit tile[1]) ----
    float* sc = &tile[0][0];
    __builtin_amdgcn_wave_barrier();
    #pragma unroll
    for (int ii = 0; ii < 4; ++ii)
        #pragma unroll
        for (int jj = 0; jj < 2; ++jj) {
            v4f a = acc[ii][jj];
            sc[(ig * 4 + ii) * SCSTR + (jg * 2 + jj)] =
                -2.0f * (a.x + a.y + a.z + a.w);
        }
    __builtin_amdgcn_wave_barrier();   // single wave: LDS in-order, just pin ordering

    // upper write: 32x16 region, coalesced b128
    #pragma unroll
    for (int s = 0; s < 2; ++s) {
        int fq = lane + 64 * s;
        int i = fq >> 2, qj = fq & 3;
        v4f val = *(const v4f*)&sc[i * SCSTR + 4 * qj];
        *(v4f*)&sOut[((size_t)b * L_ + i0 + i) * L_ + j0 + 4 * qj] = val;
    }
    // mirror write (off-diagonal tiles): 16x32 transposed region
    if (ti != tj) {
        #pragma unroll
        for (int s = 0; s < 2; ++s) {
            int fq = lane + 64 * s;
            int jm = fq >> 3, qi = fq & 7;
            v4f mv;
            mv.x = sc[(qi * 4 + 0) * SCSTR + jm];
            mv.y = sc[(qi * 4 + 1) * SCSTR + jm];
            mv.z = sc[(qi * 4 + 2) * SCSTR + jm];
            mv.w = sc[(qi * 4 + 3) * SCSTR + jm];
            *(v4f*)&sOut[((size_t)b * L_ + j0 + jm) * L_ + i0 + 4 * qi] = mv;
        }
    }
}

// Phase 2: 512 blocks x 256 thr; 4 rows/block (2 blocks/CU). Softmax in place,
// then r-phase: wave w owns j in [128w,128w+128), partial r for all 4 rows
// (H[b] read once per block), LDS reduce across waves.
__global__ __launch_bounds__(256) void softmax_r_kernel(
    const float* __restrict__ H, float* __restrict__ rOut, float* __restrict__ aOut)
{
    __shared__ float sc[4][L_];      // alpha rows, 8 KB
    __shared__ float pr[4][4][D_];   // per-wave partial r, 16 KB

    const int tid  = threadIdx.x;
    const int blk  = blockIdx.x;     // 0..511
    const int b    = blk >> 7;
    const int i0   = (blk & 127) * 4;
    const int wv   = tid >> 6;       // wave 0..3
    const int lane = tid & 63;
    const float* Hb = H + (size_t)b * L_ * D_;
    const float L2E = 1.4426950408889634f;

    // ---- softmax: wave wv handles row wv ----
    {
        const int row = wv;
        float* aRow = aOut + ((size_t)b * L_ + i0 + row) * L_;
        float v[8];
        float m = -1e30f;
        #pragma unroll
        for (int k = 0; k < 8; ++k) {
            v[k] = aRow[lane + 64 * k];      // coalesced score reads (L2-hot)
            m = fmaxf(m, v[k]);
        }
        #pragma unroll
        for (int off = 1; off < 64; off <<= 1)
            m = fmaxf(m, __shfl_xor(m, off, 64));
        float s = 0.0f;
        #pragma unroll
        for (int k = 0; k < 8; ++k) {
            v[k] = __builtin_amdgcn_exp2f((v[k] - m) * L2E);
            s += v[k];
        }
        #pragma unroll
        for (int off = 1; off < 64; off <<= 1)
            s += __shfl_xor(s, off, 64);
        const float inv = __builtin_amdgcn_rcpf(s);
        #pragma unroll
        for (int k = 0; k < 8; ++k) {
            float a = v[k] * inv;
            sc[row][lane + 64 * k] = a;
            aRow[lane + 64 * k] = a;         // overwrite scores with alpha in place
        }
    }
    __syncthreads();

    // ---- r-phase: wave-cooperative over j ----
    const int jbase = 128 * wv;
    v4f racc[4];
    #pragma unroll
    for (int r = 0; r < 4; ++r) racc[r] = (v4f){0.f, 0.f, 0.f, 0.f};
    const v4f* Hb4 = (const v4f*)Hb;         // [512][64]

    for (int js = 0; js < 128; js += 4) {
        v4f av[4];
        #pragma unroll
        for (int r = 0; r < 4; ++r)
            av[r] = *(const v4f*)&sc[r][jbase + js];   // b128 uniform broadcast
        #pragma unroll
        for (int q = 0; q < 4; ++q) {
            v4f h = Hb4[(size_t)(jbase + js + q) * (D_ / 4) + lane];
            #pragma unroll
            for (int r = 0; r < 4; ++r)
                racc[r] += av[r][q] * h;
        }
    }
    #pragma unroll
    for (int r = 0; r < 4; ++r)
        *(v4f*)&pr[wv][r][4 * lane] = racc[r];
    __syncthreads();

    // ---- reduce 4 wave-partials, write r ----
    const int fq  = tid & 63;       // float4 index in D
    const int row = tid >> 6;       // 0..3
    v4f s = *(const v4f*)&pr[0][row][4 * fq];
    s += *(const v4f*)&pr[1][row][4 * fq];
    s += *(const v4f*)&pr[2][row][4 * fq];
    s += *(const v4f*)&pr[3][row][4 * fq];
    *(v4f*)&rOut[((size_t)b * L_ + i0 + row) * D_ + 4 * fq] = s;
}

extern "C" void kernel_launch(void* const* d_in, const int* in_sizes, int n_in,
                              void* d_out, int out_size, void* d_ws, size_t ws_size,
                              hipStream_t stream) {
    const float* H = (const float*)d_in[0];
    const float* w = (const float*)d_in[1];
    // d_in[2] (bias) unused: softmax shift-invariance cancels it.
    float* rOut = (float*)d_out;
    float* aOut = rOut + (size_t)B_ * L_ * D_;   // alpha region doubles as score scratch

    score_kernel<<<dim3(B_ * NTRI * 2), 64, 0, stream>>>(H, w, aOut);
    softmax_r_kernel<<<dim3(B_ * (L_ / 4)), 256, 0, stream>>>(H, rOut, aOut);
}